// Round 11
// baseline (380.108 us; speedup 1.0000x reference)
//
#include <hip/hip_runtime.h>
#include <hip/hip_bf16.h>
#include <math.h>

#define IDIM 2048
#define NE   64
#define TOPK 8
#define NB   16384
#define BM   32            // rows per wave-block
#define NK   64            // k-steps of 32
#define TAU  5e-4f

// ws float layout: [0..63] f counts, [64..127] p sums, [128] z sum,
//                  [129] (int) flag count, [130..130+NB) (int) flagged row list
// byte WSPLIT_BYTE..: pre-split W tile images: 64 tiles x 16KB (8KB hi + 8KB lo)
#define WS_CNT 129
#define WS_LIST 130
#define WSPLIT_BYTE 66560
#define WSPLIT_REQ  (WSPLIT_BYTE + NK * 16384)

typedef __attribute__((ext_vector_type(8))) short bf16x8_t;  // 8 bf16 = 4 VGPRs
typedef __attribute__((ext_vector_type(4))) float f32x4_t;   // MFMA acc

#define MFMA __builtin_amdgcn_mfma_f32_16x16x32_bf16

__device__ __forceinline__ float softplusf(float v) {
    return (v > 0.f) ? (v + log1pf(expf(-v))) : log1pf(expf(v));
}
__device__ __forceinline__ double softplus_d(double v) {
    return (v > 0.0) ? (v + log1p(exp(-v))) : log1p(exp(v));
}

// HW RNE fp32 -> bf16 (v_cvt; deterministic)
__device__ __forceinline__ short f2bf(float f) {
    __hip_bfloat16 h = __float2bfloat16(f);
    short r; __builtin_memcpy(&r, &h, 2); return r;
}
__device__ __forceinline__ float bf2f(short s) {
    return __uint_as_float(((unsigned)(unsigned short)s) << 16);
}

__device__ __forceinline__ void split8(const float4 v0, const float4 v1,
                                       bf16x8_t& H, bf16x8_t& L) {
    float fv[8] = {v0.x, v0.y, v0.z, v0.w, v1.x, v1.y, v1.z, v1.w};
    #pragma unroll
    for (int q = 0; q < 8; ++q) {
        short hb = f2bf(fv[q]);
        H[q] = hb;
        L[q] = f2bf(fv[q] - bf2f(hb));
    }
}

__global__ void init_ws_kernel(float* ws) {
    int t = threadIdx.x;
    if (t < WS_LIST) ws[t] = 0.0f;
}

// ---------------- pass 0b: pre-split W into per-kstep tile images ----------------
// tile t (16KB): hi at col*64 + kg*16 (col 0..127, kg 0..3, 8 k-elems each), lo at +8192
__global__ __launch_bounds__(256) void prep_kernel(
    const float* __restrict__ Wg, const float* __restrict__ Wn,
    char* __restrict__ wsW)
{
    int g = blockIdx.x * 256 + threadIdx.x;   // 0..32767
    int t = g >> 9, i = g & 511;
    int col = i >> 2, kg = i & 3;
    const float* src = (col < 64 ? Wg + (size_t)col * IDIM
                                 : Wn + (size_t)(col - 64) * IDIM) + t * 32 + kg * 8;
    float4 v0 = *(const float4*)src;
    float4 v1 = *(const float4*)(src + 4);
    bf16x8_t H, L;
    split8(v0, v1, H, L);
    char* dst = wsW + (size_t)t * 16384 + col * 64 + kg * 16;
    *(bf16x8_t*)dst          = H;
    *(bf16x8_t*)(dst + 8192) = L;
}

// ---------------- pass 1: wave-standalone split-bf16 MFMA GEMM + gating ----------------
// One wave per 32 rows; B direct global->VGPR from pre-split image; no barriers.
template<bool PRE>
__global__ __launch_bounds__(64, 1) void gate_main_kernel(
    const float* __restrict__ x, const float* __restrict__ noise,
    const float* __restrict__ Wg, const float* __restrict__ bg,
    const float* __restrict__ Wn, const char* __restrict__ wsW,
    float* __restrict__ out_w, float* __restrict__ out_i,
    float* __restrict__ ws, int listCap)
{
    __shared__ float sL[32 * 132];       // 16.9 KB epilogue scratch

    const int l  = threadIdx.x;
    const int lr = l & 15;
    const int kg = l >> 4;
    const int row0 = blockIdx.x * BM;

    const float* pa0 = x + (size_t)(row0 + lr) * IDIM + kg * 8;
    const float* pa1 = pa0 + (size_t)16 * IDIM;
    const int boff = lr * 64 + kg * 16;

    const float* wrow[8];                // fallback only
    if constexpr (!PRE) {
        #pragma unroll
        for (int ct = 0; ct < 8; ++ct) {
            int col = ct * 16 + lr;
            wrow[ct] = ((col < 64) ? (Wg + (size_t)col * IDIM)
                                   : (Wn + (size_t)(col - 64) * IDIM)) + kg * 8;
        }
    }

    f32x4_t acc0[8], acc1[8];
    #pragma unroll
    for (int ct = 0; ct < 8; ++ct) {
        f32x4_t z = {0.f, 0.f, 0.f, 0.f};
        acc0[ct] = z; acc1[ct] = z;
    }

#define LOADA(R, tt) do { \
    R[0] = *(const float4*)(pa0 + (tt) * 32); \
    R[1] = *(const float4*)(pa0 + (tt) * 32 + 4); \
    R[2] = *(const float4*)(pa1 + (tt) * 32); \
    R[3] = *(const float4*)(pa1 + (tt) * 32 + 4); \
} while (0)

#define LOADB(BH, BL, tt) do { \
    if constexpr (PRE) { \
        const char* bt_ = wsW + (size_t)(tt) * 16384 + boff; \
        _Pragma("unroll") \
        for (int ct = 0; ct < 8; ++ct) { \
            BH[ct] = *(const bf16x8_t*)(bt_ + ct * 1024); \
            BL[ct] = *(const bf16x8_t*)(bt_ + 8192 + ct * 1024); \
        } \
    } else { \
        _Pragma("unroll") \
        for (int ct = 0; ct < 8; ++ct) { \
            float4 v0_ = *(const float4*)(wrow[ct] + (tt) * 32); \
            float4 v1_ = *(const float4*)(wrow[ct] + (tt) * 32 + 4); \
            split8(v0_, v1_, BH[ct], BL[ct]); \
        } \
    } \
} while (0)

#define KSTEP(BH, BL, NBH, NBL, RA, NRA, tnext) do { \
    bf16x8_t ah0, al0, ah1, al1; \
    split8(RA[0], RA[1], ah0, al0); \
    split8(RA[2], RA[3], ah1, al1); \
    LOADA(NRA, tnext); \
    LOADB(NBH, NBL, tnext); \
    _Pragma("unroll") \
    for (int ct = 0; ct < 8; ++ct) { \
        acc0[ct] = MFMA(ah0, BH[ct], acc0[ct], 0, 0, 0); \
        acc1[ct] = MFMA(ah1, BH[ct], acc1[ct], 0, 0, 0); \
        acc0[ct] = MFMA(ah0, BL[ct], acc0[ct], 0, 0, 0); \
        acc1[ct] = MFMA(ah1, BL[ct], acc1[ct], 0, 0, 0); \
        acc0[ct] = MFMA(al0, BH[ct], acc0[ct], 0, 0, 0); \
        acc1[ct] = MFMA(al1, BH[ct], acc1[ct], 0, 0, 0); \
    } \
} while (0)

    float4   rA0[4], rA1[4];
    bf16x8_t bh0[8], bl0[8], bh1[8], bl1[8];

    LOADA(rA0, 0);
    LOADB(bh0, bl0, 0);

    for (int t = 0; t < NK; t += 2) {
        KSTEP(bh0, bl0, bh1, bl1, rA0, rA1, t + 1);
        KSTEP(bh1, bl1, bh0, bl0, rA1, rA0, (t + 2) & (NK - 1));
    }

    // ---- epilogue: acc -> sL[32][132]  (C/D: col=lane&15, row=(lane>>4)*4+reg) ----
    #pragma unroll
    for (int ct = 0; ct < 8; ++ct)
        #pragma unroll
        for (int r = 0; r < 4; ++r) {
            sL[(kg * 4 + r) * 132 + ct * 16 + lr]        = acc0[ct][r];
            sL[(16 + kg * 4 + r) * 132 + ct * 16 + lr]   = acc1[ct][r];
        }
    __syncthreads();   // single wave: cheap; orders LDS writes before reads

    // ---- gating: 32 rows serial, lane = expert ----
    const float bgl = bg[l];
    float pacc = 0.f, zacc = 0.f;
    int   fcnt = 0;

    #pragma unroll 1
    for (int rr = 0; rr < 32; ++rr) {
        const int grow = row0 + rr;
        float lg   = sL[rr * 132 + l] + bgl;
        float npre = sL[rr * 132 + 64 + l];
        float vcur = fmaf(noise[(size_t)grow * NE + l], softplusf(npre), lg);

        float tkv[9]; int tki[9];
        #pragma unroll
        for (int k = 0; k < 9; ++k) {
            float mv = vcur; int mi = l;
            #pragma unroll
            for (int o = 32; o > 0; o >>= 1) {
                float ov = __shfl_xor(mv, o);
                int   oi = __shfl_xor(mi, o);
                if (ov > mv || (ov == mv && oi < mi)) { mv = ov; mi = oi; }
            }
            tkv[k] = mv; tki[k] = mi;
            if (l == mi) vcur = -1e30f;
        }

        float m0 = tkv[0], s = 0.f, wk[TOPK];
        #pragma unroll
        for (int k = 0; k < TOPK; ++k) { wk[k] = expf(tkv[k] - m0); s += wk[k]; }
        float inv = 1.f / s;
        float myw = 0.f; int myi = 0;
        #pragma unroll
        for (int k = 0; k < TOPK; ++k)
            if (l == k) { myw = wk[k] * inv; myi = tki[k]; }
        if (l < TOPK) {
            out_w[(size_t)grow * TOPK + l] = myw;
            out_i[(size_t)grow * TOPK + l] = (float)myi;
        }

        fcnt += (tki[0] == l) ? 1 : 0;   // per-lane argmax histogram

        if (l == 0) {
            float ming = 1e30f;
            #pragma unroll
            for (int k = 0; k < 8; ++k) ming = fminf(ming, tkv[k] - tkv[k + 1]);
            if (ming < TAU) {
                int slot = atomicAdd((int*)&ws[WS_CNT], 1);
                if (slot < listCap) ((int*)ws)[WS_LIST + slot] = grow;
            }
        }

        float rm = lg;
        #pragma unroll
        for (int o = 32; o > 0; o >>= 1) rm = fmaxf(rm, __shfl_xor(rm, o));
        float pe = expf(lg - rm);
        float ssum = pe;
        #pragma unroll
        for (int o = 32; o > 0; o >>= 1) ssum += __shfl_xor(ssum, o);
        pacc += pe / ssum;
        float lse = rm + logf(ssum);
        zacc += lse * lse;               // identical on all lanes
    }

    atomicAdd(&ws[l],      (float)fcnt);
    atomicAdd(&ws[NE + l], pacc);
    if (l == 0) atomicAdd(&ws[2 * NE], zacc);
}

// ---------------- pass 2: finalize scalars (block 0) + fp64 recheck, 1 row/block ----------------
// 512 threads = 128 dot-slots (0..63 Wg expert, 64..127 Wn expert) x 4 K-quarters.
__global__ __launch_bounds__(512) void recheck_finalize_kernel(
    const float* __restrict__ x, const float* __restrict__ noise,
    const float* __restrict__ Wg, const float* __restrict__ bg,
    const float* __restrict__ Wn,
    float* __restrict__ out_w, float* __restrict__ out_i, float* __restrict__ out_s,
    const float* __restrict__ ws, int listCap)
{
    __shared__ double sRed[512];
    const int t = threadIdx.x;

    if (blockIdx.x == 0 && t < 64) {     // finalize scalars (wave 0, no barriers)
        float v = (ws[t] / (float)NB) * (ws[NE + t] / (float)NB);
        #pragma unroll
        for (int o = 32; o > 0; o >>= 1) v += __shfl_down(v, o);
        if (t == 0) {
            out_s[0] = (float)NE * v;
            out_s[1] = ws[2 * NE] / (float)NB;
        }
    }

    const int* wsi = (const int*)ws;
    int cnt = wsi[WS_CNT];
    if (cnt > listCap) cnt = listCap;
    if (cnt <= 0) return;

    const int slot = t & 127;            // 0..63: Wg expert; 64..127: Wn expert-64
    const int q4   = t >> 7;             // K quarter
    const float* wrb = ((slot < 64) ? (Wg + (size_t)slot * IDIM)
                                    : (Wn + (size_t)(slot - 64) * IDIM)) + q4 * 512;

    for (int bi = blockIdx.x; bi < cnt; bi += gridDim.x) {
        const int row = wsi[WS_LIST + bi];
        const float* xr = x + (size_t)row * IDIM + q4 * 512;

        double a = 0.0;
        #pragma unroll 4
        for (int k = 0; k < 512; k += 4) {
            float4 wv = *(const float4*)(wrb + k);
            float4 xv = *(const float4*)(xr + k);
            a = fma((double)xv.x, (double)wv.x, a);
            a = fma((double)xv.y, (double)wv.y, a);
            a = fma((double)xv.z, (double)wv.z, a);
            a = fma((double)xv.w, (double)wv.w, a);
        }
        sRed[t] = a;
        __syncthreads();
        if (t < 128)
            sRed[t] = sRed[t] + sRed[t + 128] + sRed[t + 256] + sRed[t + 384];
        __syncthreads();

        if (t < 64) {
            const int lane = t;
            double g = sRed[lane];
            double n = sRed[64 + lane];
            double lgd = g + (double)bg[lane];
            double nz = (double)noise[(size_t)row * NE + lane];
            double vcur = fma(nz, softplus_d(n), lgd);

            double tkv[TOPK]; int tki[TOPK];
            #pragma unroll
            for (int k = 0; k < TOPK; ++k) {
                double mv = vcur; int mi = lane;
                #pragma unroll
                for (int o = 32; o > 0; o >>= 1) {
                    double ov = __shfl_xor(mv, o);
                    int    oi = __shfl_xor(mi, o);
                    if (ov > mv || (ov == mv && oi < mi)) { mv = ov; mi = oi; }
                }
                tkv[k] = mv; tki[k] = mi;
                if (lane == mi) vcur = -1e300;
            }
            double m0 = tkv[0], s = 0.0, wk[TOPK];
            #pragma unroll
            for (int k = 0; k < TOPK; ++k) { wk[k] = exp(tkv[k] - m0); s += wk[k]; }
            double inv = 1.0 / s;
            float myw = 0.f; int myi = 0;
            #pragma unroll
            for (int k = 0; k < TOPK; ++k)
                if (lane == k) { myw = (float)(wk[k] * inv); myi = tki[k]; }
            if (lane < TOPK) {
                out_w[(size_t)row * TOPK + lane] = myw;
                out_i[(size_t)row * TOPK + lane] = (float)myi;
            }
        }
        __syncthreads();   // sRed reuse safe
    }
}

extern "C" void kernel_launch(void* const* d_in, const int* in_sizes, int n_in,
                              void* d_out, int out_size, void* d_ws, size_t ws_size,
                              hipStream_t stream) {
    const float* x     = (const float*)d_in[0];
    const float* noise = (const float*)d_in[1];
    const float* Wg    = (const float*)d_in[2];
    const float* bg    = (const float*)d_in[3];
    const float* Wn    = (const float*)d_in[4];
    float* out = (float*)d_out;
    float* ws  = (float*)d_ws;
    char*  wsW = (char*)d_ws + WSPLIT_BYTE;

    long cap = (long)(ws_size / 4) - WS_LIST;
    int listCap = (int)(cap < 0 ? 0 : (cap > NB ? NB : cap));
    const bool pre = ws_size >= (size_t)WSPLIT_REQ;

    hipLaunchKernelGGL(init_ws_kernel, dim3(1), dim3(256), 0, stream, ws);
    if (pre) {
        hipLaunchKernelGGL(prep_kernel, dim3(128), dim3(256), 0, stream, Wg, Wn, wsW);
        hipLaunchKernelGGL(gate_main_kernel<true>, dim3(NB / BM), dim3(64), 0, stream,
                           x, noise, Wg, bg, Wn, wsW,
                           out, out + (size_t)NB * TOPK, ws, listCap);
    } else {
        hipLaunchKernelGGL(gate_main_kernel<false>, dim3(NB / BM), dim3(64), 0, stream,
                           x, noise, Wg, bg, Wn, wsW,
                           out, out + (size_t)NB * TOPK, ws, listCap);
    }
    hipLaunchKernelGGL(recheck_finalize_kernel, dim3(1024), dim3(512), 0, stream,
                       x, noise, Wg, bg, Wn,
                       out, out + (size_t)NB * TOPK, out + 2 * (size_t)NB * TOPK,
                       ws, listCap);
}

// Round 12
// 169.732 us; speedup vs baseline: 2.2395x; 2.2395x over previous
//
#include <hip/hip_runtime.h>
#include <math.h>

#define IDIM 2048
#define NE   64
#define TOPK 8
#define NB   16384
#define BM   32            // rows per block
#define BK   64            // k per staged tile
#define NCH  (IDIM / BK)   // 32 tiles
#define TAU  5e-4f

// ws float layout: [0..63] f counts, [64..127] p sums, [128] z sum,
//                  [129] (int) flag count, [130..130+NB) (int) flagged row list
// byte WSPLIT_BYTE..: pre-split W tile images (32 tiles x (16KB hi + 16KB lo)),
//                     laid out EXACTLY as the LDS tile (swizzle baked in).
#define WS_CNT 129
#define WS_LIST 130
#define WSPLIT_BYTE 66560
#define WSPLIT_REQ  (WSPLIT_BYTE + NCH * 32768)

typedef __attribute__((ext_vector_type(8))) short bf16x8_t;  // 8 bf16 = 4 VGPRs
typedef __attribute__((ext_vector_type(4))) short bf16x4_t;  // 4 bf16 = 2 VGPRs
typedef __attribute__((ext_vector_type(4))) float f32x4_t;   // MFMA acc

#define MFMA __builtin_amdgcn_mfma_f32_16x16x32_bf16

// Workgroup barrier WITHOUT vmcnt drain: LDS ops fenced, global/DMA loads stay in flight.
#define LDS_BARRIER() do {                                   \
    asm volatile("s_waitcnt lgkmcnt(0)" ::: "memory");       \
    __builtin_amdgcn_sched_barrier(0);                       \
    __builtin_amdgcn_s_barrier();                            \
    __builtin_amdgcn_sched_barrier(0);                       \
} while (0)

__device__ __forceinline__ float softplusf(float v) {
    return (v > 0.f) ? (v + log1pf(expf(-v))) : log1pf(expf(v));
}
__device__ __forceinline__ double softplus_d(double v) {
    return (v > 0.0) ? (v + log1p(exp(-v))) : log1p(exp(v));
}

// deterministic RNE fp32 -> bf16 bits
__device__ __forceinline__ short f2bf(float f) {
    unsigned u = __float_as_uint(f);
    unsigned r = (u + 0x7FFFu + ((u >> 16) & 1u)) >> 16;
    return (short)r;
}
__device__ __forceinline__ float bf2f(short s) {
    return __uint_as_float(((unsigned)(unsigned short)s) << 16);
}

__global__ void init_ws_kernel(float* ws) {
    int t = threadIdx.x;
    if (t < WS_LIST) ws[t] = 0.0f;
}

__device__ __forceinline__ void split8(const float4 v0, const float4 v1,
                                       bf16x8_t& H, bf16x8_t& L) {
    float fv[8] = {v0.x, v0.y, v0.z, v0.w, v1.x, v1.y, v1.z, v1.w};
    #pragma unroll
    for (int q = 0; q < 8; ++q) {
        short hb = f2bf(fv[q]);
        H[q] = hb;
        L[q] = f2bf(fv[q] - bf2f(hb));
    }
}

__device__ __forceinline__ void cvt_slot(const float4 v0, const float4 v1,
                                         char* hiP, char* loP, int off) {
    bf16x8_t H, L;
    split8(v0, v1, H, L);
    *(bf16x8_t*)(hiP + off) = H;
    *(bf16x8_t*)(loP + off) = L;
}

// ---------------- pass 0b: pre-split W into swizzled LDS tile images ----------------
// tile t (32KB): hi byte (row*128 + wslot*16) holds k-group (wslot ^ (row&7)); lo at +16384
__global__ __launch_bounds__(256) void prep_kernel(
    const float* __restrict__ Wg, const float* __restrict__ Wn,
    char* __restrict__ wsW)
{
    int g = blockIdx.x * 256 + threadIdx.x;   // 0..32767
    int t = g >> 10, i = g & 1023;
    int row = i >> 3, wslot = i & 7;
    int kslot = wslot ^ (row & 7);
    const float* src = (row < 64 ? Wg + (size_t)row * IDIM
                                 : Wn + (size_t)(row - 64) * IDIM) + t * BK + kslot * 8;
    float4 v0 = *(const float4*)src;
    float4 v1 = *(const float4*)(src + 4);
    bf16x8_t H, L;
    split8(v0, v1, H, L);
    char* dst = wsW + (size_t)t * 32768;
    *(bf16x8_t*)(dst + i * 16)         = H;
    *(bf16x8_t*)(dst + 16384 + i * 16) = L;
}

// ---------------- pass 1: split-bf16 MFMA GEMM, DMA W staging + gating ----------------
// LDS (81920B): abuf0@0 (AH 4K + AL 4K), abuf1@8192, wbuf0@16384 (32K), wbuf1@49152 (32K)
//   epilogue alias: sL f32[32][132] @0 ; sP@16896 sF@17152 sZ@17408 (init post-loop)
template<bool PRE>
__global__ __launch_bounds__(512, 4) void gate_main_kernel(
    const float* __restrict__ x, const float* __restrict__ noise,
    const float* __restrict__ Wg, const float* __restrict__ bg,
    const float* __restrict__ Wn, const char* __restrict__ wsW,
    float* __restrict__ out_w, float* __restrict__ out_i,
    float* __restrict__ ws, int listCap)
{
    __shared__ char smem[81920] __attribute__((aligned(16)));

    const int u   = threadIdx.x;
    const int w   = u >> 6;              // wave 0..7, owns cols [w*16, w*16+16)
    const int l   = u & 63;
    const int lr  = l & 15;
    const int lg4 = l >> 4;
    const int s7  = lr & 7;
    const int row0 = blockIdx.x * BM;

    // A staging: all 512 threads, one dwordx4 (4 floats) each, swizzle-baked source
    const int arow = u >> 4;             // 0..31
    const int ah_  = u & 15;             // 8B half-slot
    const int as16 = ah_ >> 1;
    const int ahh  = ah_ & 1;
    const int agrp = as16 ^ (arow & 7);
    const float* paA = x + (size_t)(row0 + arow) * IDIM + agrp * 8 + ahh * 4;
    const int aoff = arow * 128 + as16 * 16 + ahh * 8;

    // W DMA offsets (PRE)
    const int dmaL = w * 4096;           // wave-uniform LDS offset within wbuf
    const int dmaG = dmaL + l * 16;      // per-lane global offset within image tile

    // fallback W staging (reg + cvt route)
    const int br  = u >> 3;              // 0..63
    const int ac  = u & 7;
    const float* pg = Wg + (size_t)br * IDIM + ac * 8;
    const float* pn = Wn + (size_t)br * IDIM + ac * 8;
    const int woff = br * 128 + ((ac ^ (br & 7)) << 4);

    f32x4_t acc0 = {0.f, 0.f, 0.f, 0.f};
    f32x4_t acc1 = {0.f, 0.f, 0.f, 0.f};
    float4 rA;

#define LOADA(tt) { rA = *(const float4*)(paA + (tt) * BK); }

#define CVTA(bufi) do {                                         \
    char* ab_ = smem + (bufi) * 8192;                           \
    float fv[4] = {rA.x, rA.y, rA.z, rA.w};                     \
    bf16x4_t H_, L_;                                            \
    _Pragma("unroll")                                           \
    for (int q_ = 0; q_ < 4; ++q_) {                            \
        short hb_ = f2bf(fv[q_]);                               \
        H_[q_] = hb_;                                           \
        L_[q_] = f2bf(fv[q_] - bf2f(hb_));                      \
    }                                                           \
    *(bf16x4_t*)(ab_ + aoff)        = H_;                       \
    *(bf16x4_t*)(ab_ + 4096 + aoff) = L_;                       \
} while (0)

#define DMAW(tt, bufi) do {                                                     \
    const char* img_ = wsW + (size_t)(tt) * 32768 + dmaG;                       \
    char* wb_ = smem + 16384 + (bufi) * 32768 + dmaL;                           \
    _Pragma("unroll")                                                           \
    for (int j_ = 0; j_ < 4; ++j_)                                              \
        __builtin_amdgcn_global_load_lds(                                       \
            (const __attribute__((address_space(1))) void*)(img_ + j_ * 1024),  \
            (__attribute__((address_space(3))) void*)(wb_ + j_ * 1024),         \
            16, 0, 0);                                                          \
} while (0)

#define FSTAGE(tt, bufi) do {                                   \
    char* wb_ = smem + 16384 + (bufi) * 32768;                  \
    const int k0_ = (tt) * BK;                                  \
    float4 g0_ = *(const float4*)(pg + k0_);                    \
    float4 g1_ = *(const float4*)(pg + k0_ + 4);                \
    float4 n0_ = *(const float4*)(pn + k0_);                    \
    float4 n1_ = *(const float4*)(pn + k0_ + 4);                \
    cvt_slot(g0_, g1_, wb_, wb_ + 16384, woff);                 \
    cvt_slot(n0_, n1_, wb_, wb_ + 16384, woff + 8192);          \
} while (0)

    // ---- prologue: stage tile 0 (A+W), issue tile-1 loads ----
    LOADA(0);
    CVTA(0);                             // auto-waits A(0)
    if constexpr (PRE) {
        DMAW(0, 0);
        LOADA(1);
        DMAW(1, 1);
        asm volatile("s_waitcnt vmcnt(5)" ::: "memory");  // DMA(0) done; A(1)+DMA(1) in flight
        __builtin_amdgcn_sched_barrier(0);
    } else {
        FSTAGE(0, 0);
        FSTAGE(1, 1);
        LOADA(1);
    }
    LDS_BARRIER();

    int cur = 0;
    for (int t = 0; t < NCH; ++t, cur ^= 1) {
        // ---- compute tile t ----
        {
            char* ab = smem + cur * 8192;
            char* wb = smem + 16384 + cur * 32768;
            #pragma unroll
            for (int ks = 0; ks < 2; ++ks) {
                const int so = (((ks * 4 + lg4) ^ s7) << 4);
                bf16x8_t ah0 = *(const bf16x8_t*)(ab + lr * 128 + so);
                bf16x8_t ah1 = *(const bf16x8_t*)(ab + (16 + lr) * 128 + so);
                bf16x8_t al0 = *(const bf16x8_t*)(ab + 4096 + lr * 128 + so);
                bf16x8_t al1 = *(const bf16x8_t*)(ab + 4096 + (16 + lr) * 128 + so);
                bf16x8_t bh  = *(const bf16x8_t*)(wb + (w * 16 + lr) * 128 + so);
                bf16x8_t bl  = *(const bf16x8_t*)(wb + 16384 + (w * 16 + lr) * 128 + so);
                acc0 = MFMA(ah0, bh, acc0, 0, 0, 0);
                acc0 = MFMA(ah0, bl, acc0, 0, 0, 0);
                acc0 = MFMA(al0, bh, acc0, 0, 0, 0);
                acc1 = MFMA(ah1, bh, acc1, 0, 0, 0);
                acc1 = MFMA(ah1, bl, acc1, 0, 0, 0);
                acc1 = MFMA(al1, bh, acc1, 0, 0, 0);
            }
        }
        if (t + 1 == NCH) break;
        LDS_BARRIER();                   // all reads of bufs[cur] done
        CVTA(cur ^ 1);                   // A(t+1): auto vmcnt(0) also confirms DMA(t+1)
        if (t + 2 < NCH) {
            if constexpr (PRE) DMAW(t + 2, cur); else FSTAGE(t + 2, cur);
            LOADA(t + 2);                // stays in flight across barrier + compute(t+1)
        }
        LDS_BARRIER();                   // A(t+1) writes visible; DMA(t+1) confirmed by all
    }
    __syncthreads();                     // full drain; staging dead; safe to alias

    // ---- epilogue: acc -> sL[32][132]  (C/D: col=lane&15, row=(lane>>4)*4+reg) ----
    float* sL = (float*)smem;
    float* sP = (float*)(smem + 16896);
    float* sF = (float*)(smem + 17152);
    float* sZ = (float*)(smem + 17408);
    if (u < NE) { sP[u] = 0.f; sF[u] = 0.f; }
    if (u == 0) sZ[0] = 0.f;
    #pragma unroll
    for (int r = 0; r < 4; ++r) {
        sL[(lg4 * 4 + r) * 132 + (w * 16 + lr)]      = acc0[r];
        sL[(16 + lg4 * 4 + r) * 132 + (w * 16 + lr)] = acc1[r];
    }
    __syncthreads();

    // ---- gating: 8 waves x 4 rows, lane = expert ----
    float pacc = 0.f, zacc = 0.f;
    #pragma unroll 1
    for (int rr = 0; rr < 4; ++rr) {
        const int r = w * 4 + rr;
        const int grow = row0 + r;
        float lg   = sL[r * 132 + l] + bg[l];
        float npre = sL[r * 132 + 64 + l];
        float vcur = fmaf(noise[(size_t)grow * NE + l], softplusf(npre), lg);

        float tkv[9]; int tki[9];
        #pragma unroll
        for (int k = 0; k < 9; ++k) {
            float mv = vcur; int mi = l;
            #pragma unroll
            for (int o = 32; o > 0; o >>= 1) {
                float ov = __shfl_xor(mv, o);
                int   oi = __shfl_xor(mi, o);
                if (ov > mv || (ov == mv && oi < mi)) { mv = ov; mi = oi; }
            }
            tkv[k] = mv; tki[k] = mi;
            if (l == mi) vcur = -1e30f;
        }

        float m0 = tkv[0], s = 0.f, wk[TOPK];
        #pragma unroll
        for (int k = 0; k < TOPK; ++k) { wk[k] = expf(tkv[k] - m0); s += wk[k]; }
        float inv = 1.f / s;
        float myw = 0.f; int myi = 0;
        #pragma unroll
        for (int k = 0; k < TOPK; ++k)
            if (l == k) { myw = wk[k] * inv; myi = tki[k]; }
        if (l < TOPK) {
            out_w[(size_t)grow * TOPK + l] = myw;
            out_i[(size_t)grow * TOPK + l] = (float)myi;
        }

        if (l == 0) {
            atomicAdd(&sF[tki[0]], 1.f);
            float ming = 1e30f;
            #pragma unroll
            for (int k = 0; k < 8; ++k) ming = fminf(ming, tkv[k] - tkv[k + 1]);
            if (ming < TAU) {
                int slot = atomicAdd((int*)&ws[WS_CNT], 1);
                if (slot < listCap) ((int*)ws)[WS_LIST + slot] = grow;
            }
        }

        float rm = lg;
        #pragma unroll
        for (int o = 32; o > 0; o >>= 1) rm = fmaxf(rm, __shfl_xor(rm, o));
        float pe = expf(lg - rm);
        float ssum = pe;
        #pragma unroll
        for (int o = 32; o > 0; o >>= 1) ssum += __shfl_xor(ssum, o);
        pacc += pe / ssum;
        if (l == 0) { float lse = rm + logf(ssum); zacc += lse * lse; }
    }

    atomicAdd(&sP[l], pacc);
    if (l == 0) atomicAdd(sZ, zacc);
    __syncthreads();
    if (u < NE) {
        atomicAdd(&ws[u],      sF[u]);
        atomicAdd(&ws[NE + u], sP[u]);
    }
    if (u == 0) atomicAdd(&ws[2 * NE], sZ[0]);
}

// ---------------- pass 2: finalize scalars (block 0) + fp64 recheck, 1 row/block ----------------
__global__ __launch_bounds__(512) void recheck_finalize_kernel(
    const float* __restrict__ x, const float* __restrict__ noise,
    const float* __restrict__ Wg, const float* __restrict__ bg,
    const float* __restrict__ Wn,
    float* __restrict__ out_w, float* __restrict__ out_i, float* __restrict__ out_s,
    const float* __restrict__ ws, int listCap)
{
    __shared__ double sRed[512];
    const int t = threadIdx.x;

    if (blockIdx.x == 0 && t < 64) {
        float v = (ws[t] / (float)NB) * (ws[NE + t] / (float)NB);
        #pragma unroll
        for (int o = 32; o > 0; o >>= 1) v += __shfl_down(v, o);
        if (t == 0) {
            out_s[0] = (float)NE * v;
            out_s[1] = ws[2 * NE] / (float)NB;
        }
    }

    const int* wsi = (const int*)ws;
    int cnt = wsi[WS_CNT];
    if (cnt > listCap) cnt = listCap;
    if (cnt <= 0) return;

    const int slot = t & 127;
    const int q4   = t >> 7;
    const float* wrb = ((slot < 64) ? (Wg + (size_t)slot * IDIM)
                                    : (Wn + (size_t)(slot - 64) * IDIM)) + q4 * 512;

    for (int bi = blockIdx.x; bi < cnt; bi += gridDim.x) {
        const int row = wsi[WS_LIST + bi];
        const float* xr = x + (size_t)row * IDIM + q4 * 512;

        double a = 0.0;
        #pragma unroll 4
        for (int k = 0; k < 512; k += 4) {
            float4 wv = *(const float4*)(wrb + k);
            float4 xv = *(const float4*)(xr + k);
            a = fma((double)xv.x, (double)wv.x, a);
            a = fma((double)xv.y, (double)wv.y, a);
            a = fma((double)xv.z, (double)wv.z, a);
            a = fma((double)xv.w, (double)wv.w, a);
        }
        sRed[t] = a;
        __syncthreads();
        if (t < 128)
            sRed[t] = sRed[t] + sRed[t + 128] + sRed[t + 256] + sRed[t + 384];
        __syncthreads();

        if (t < 64) {
            const int lane = t;
            double g = sRed[lane];
            double n = sRed[64 + lane];
            double lgd = g + (double)bg[lane];
            double nz = (double)noise[(size_t)row * NE + lane];
            double vcur = fma(nz, softplus_d(n), lgd);

            double tkv[TOPK]; int tki[TOPK];
            #pragma unroll
            for (int k = 0; k < TOPK; ++k) {
                double mv = vcur; int mi = lane;
                #pragma unroll
                for (int o = 32; o > 0; o >>= 1) {
                    double ov = __shfl_xor(mv, o);
                    int    oi = __shfl_xor(mi, o);
                    if (ov > mv || (ov == mv && oi < mi)) { mv = ov; mi = oi; }
                }
                tkv[k] = mv; tki[k] = mi;
                if (lane == mi) vcur = -1e300;
            }
            double m0 = tkv[0], s = 0.0, wk[TOPK];
            #pragma unroll
            for (int k = 0; k < TOPK; ++k) { wk[k] = exp(tkv[k] - m0); s += wk[k]; }
            double inv = 1.0 / s;
            float myw = 0.f; int myi = 0;
            #pragma unroll
            for (int k = 0; k < TOPK; ++k)
                if (lane == k) { myw = (float)(wk[k] * inv); myi = tki[k]; }
            if (lane < TOPK) {
                out_w[(size_t)row * TOPK + lane] = myw;
                out_i[(size_t)row * TOPK + lane] = (float)myi;
            }
        }
        __syncthreads();
    }
}

extern "C" void kernel_launch(void* const* d_in, const int* in_sizes, int n_in,
                              void* d_out, int out_size, void* d_ws, size_t ws_size,
                              hipStream_t stream) {
    const float* x     = (const float*)d_in[0];
    const float* noise = (const float*)d_in[1];
    const float* Wg    = (const float*)d_in[2];
    const float* bg    = (const float*)d_in[3];
    const float* Wn    = (const float*)d_in[4];
    float* out = (float*)d_out;
    float* ws  = (float*)d_ws;
    char*  wsW = (char*)d_ws + WSPLIT_BYTE;

    long cap = (long)(ws_size / 4) - WS_LIST;
    int listCap = (int)(cap < 0 ? 0 : (cap > NB ? NB : cap));
    const bool pre = ws_size >= (size_t)WSPLIT_REQ;

    hipLaunchKernelGGL(init_ws_kernel, dim3(1), dim3(256), 0, stream, ws);
    if (pre) {
        hipLaunchKernelGGL(prep_kernel, dim3(128), dim3(256), 0, stream, Wg, Wn, wsW);
        hipLaunchKernelGGL(gate_main_kernel<true>, dim3(NB / BM), dim3(512), 0, stream,
                           x, noise, Wg, bg, Wn, wsW,
                           out, out + (size_t)NB * TOPK, ws, listCap);
    } else {
        hipLaunchKernelGGL(gate_main_kernel<false>, dim3(NB / BM), dim3(512), 0, stream,
                           x, noise, Wg, bg, Wn, wsW,
                           out, out + (size_t)NB * TOPK, ws, listCap);
    }
    hipLaunchKernelGGL(recheck_finalize_kernel, dim3(1024), dim3(512), 0, stream,
                       x, noise, Wg, bg, Wn,
                       out, out + (size_t)NB * TOPK, out + 2 * (size_t)NB * TOPK,
                       ws, listCap);
}